// Round 1
// baseline (794.708 us; speedup 1.0000x reference)
//
#include <hip/hip_runtime.h>
#include <math.h>

#define B_SZ 16384
#define F_N 39
#define V_N 30000
#define D_N 16
#define K_SEL 20
#define FD 624   // F_N * D_N

// ---------------------------------------------------------------------------
// Kernel 1: per-sample gather + controller MLP + softmax + top-K mask + weight
// One 64-thread wave per batch row.
// z[b, d*F + f] = (f in topK(scores)) ? scores[f] * emb[b,f,d] : 0
// ---------------------------------------------------------------------------
__global__ __launch_bounds__(64) void controller_select_kernel(
    const int* __restrict__ x, const float* __restrict__ emb_table,
    const float* __restrict__ w_c, const float* __restrict__ b_c,
    const float* __restrict__ g_c, const float* __restrict__ be_c,
    float* __restrict__ z)
{
    __shared__ float flat[FD];   // flat[d*39+f] = emb[f][d]  (reference layout)
    __shared__ float sc[F_N];    // h, then scores
    __shared__ float wsel[F_N];  // selected ? score : 0
    __shared__ int   rowidx[F_N];

    const int b = blockIdx.x;
    const int t = threadIdx.x;

    if (t < F_N) rowidx[t] = x[b * F_N + t] + t * V_N;
    __syncthreads();

    // gather: 4 fields per iteration, 16 lanes per field (coalesced 64B rows)
    const int fq = t >> 4;   // 0..3
    const int d  = t & 15;
    for (int fb = 0; fb < 40; fb += 4) {
        int f = fb + fq;
        if (f < F_N) {
            float v = emb_table[(size_t)rowidx[f] * D_N + d];
            flat[d * F_N + f] = v;
        }
    }
    __syncthreads();

    // h[f] = relu(bn(dot(flat, w_c[f,:]) + b_c[f]))
    const float rs = rsqrtf(1.0f + 1e-5f);
    if (t < F_N) {
        const float* wrow = w_c + t * FD;
        float s = 0.f;
        #pragma unroll 4
        for (int j = 0; j < FD; ++j) s += flat[j] * wrow[j];
        s += b_c[t];
        s = g_c[t] * s * rs + be_c[t];
        sc[t] = fmaxf(s, 0.f);
    }
    __syncthreads();

    // softmax over 39 fields (redundant per-lane; cheap)
    float mx = -1e30f;
    for (int f = 0; f < F_N; ++f) mx = fmaxf(mx, sc[f]);
    float sum = 0.f;
    for (int f = 0; f < F_N; ++f) sum += expf(sc[f] - mx);
    float mysc = (t < F_N) ? expf(sc[t] - mx) / sum : 0.f;
    __syncthreads();
    if (t < F_N) sc[t] = mysc;
    __syncthreads();

    // top-K mask, lax.top_k tie-break: larger value first, ties -> lower index
    if (t < F_N) {
        int rank = 0;
        for (int f = 0; f < F_N; ++f) {
            float o = sc[f];
            if (o > mysc || (o == mysc && f < t)) rank++;
        }
        wsel[t] = (rank < K_SEL) ? mysc : 0.f;
    }
    __syncthreads();

    // z[b, j] = wsel[j % 39] * flat[j]   (j = d*39+f), coalesced store
    float* zrow = z + (size_t)b * FD;
    for (int j = t; j < FD; j += 64)
        zrow[j] = wsel[j % F_N] * flat[j];
}

// ---------------------------------------------------------------------------
// Kernel 2/3: C[M,N] = relu(bn(A[M,K] @ W[N,K]^T + bias))
// 64x64 tile, 256 threads, 4x4 microtile, K-tile 16.  fp32.
// ---------------------------------------------------------------------------
#define TM 64
#define TN 64
#define TKK 16
#define LDT 68   // padded leading dim (16B-aligned rows, breaks pow2 strides)

__global__ __launch_bounds__(256) void gemm_bn_relu_kernel(
    const float* __restrict__ A, const float* __restrict__ W,
    const float* __restrict__ bias, const float* __restrict__ g,
    const float* __restrict__ be, float* __restrict__ C,
    int M, int N, int K)
{
    __shared__ float As[TKK * LDT];  // As[k][m]
    __shared__ float Ws[TKK * LDT];  // Ws[k][n]

    const int t  = threadIdx.x;
    const int m0 = blockIdx.y * TM;
    const int n0 = blockIdx.x * TN;
    const int tx = t & 15;        // n-group
    const int ty = t >> 4;        // m-group
    const int lr = t >> 2;        // 0..63: tile row for loading
    const int lk = (t & 3) * 4;   // k offset 0,4,8,12

    float acc[4][4] = {};

    for (int k0 = 0; k0 < K; k0 += TKK) {
        float4 av = *reinterpret_cast<const float4*>(A + (size_t)(m0 + lr) * K + k0 + lk);
        float4 wv = *reinterpret_cast<const float4*>(W + (size_t)(n0 + lr) * K + k0 + lk);
        __syncthreads();
        As[(lk + 0) * LDT + lr] = av.x;
        As[(lk + 1) * LDT + lr] = av.y;
        As[(lk + 2) * LDT + lr] = av.z;
        As[(lk + 3) * LDT + lr] = av.w;
        Ws[(lk + 0) * LDT + lr] = wv.x;
        Ws[(lk + 1) * LDT + lr] = wv.y;
        Ws[(lk + 2) * LDT + lr] = wv.z;
        Ws[(lk + 3) * LDT + lr] = wv.w;
        __syncthreads();

        #pragma unroll
        for (int k = 0; k < TKK; ++k) {
            float4 a4 = *reinterpret_cast<const float4*>(&As[k * LDT + ty * 4]);
            float4 b4 = *reinterpret_cast<const float4*>(&Ws[k * LDT + tx * 4]);
            const float aa[4] = {a4.x, a4.y, a4.z, a4.w};
            const float bb[4] = {b4.x, b4.y, b4.z, b4.w};
            #pragma unroll
            for (int i = 0; i < 4; ++i)
                #pragma unroll
                for (int j = 0; j < 4; ++j)
                    acc[i][j] = fmaf(aa[i], bb[j], acc[i][j]);
        }
    }

    const float rs = rsqrtf(1.0f + 1e-5f);
    #pragma unroll
    for (int i = 0; i < 4; ++i) {
        const int m = m0 + ty * 4 + i;
        const int nb = n0 + tx * 4;
        float4 o;
        float* op = &o.x;
        #pragma unroll
        for (int j = 0; j < 4; ++j) {
            const int n = nb + j;
            float v = acc[i][j] + bias[n];
            v = g[n] * v * rs + be[n];
            op[j] = fmaxf(v, 0.f);
        }
        *reinterpret_cast<float4*>(C + (size_t)m * N + nb) = o;
    }
}

// ---------------------------------------------------------------------------
// Kernel 4: out[b] = sigmoid(dot(h1[b,:512], w_out) + b_out)
// 4 waves per block, one wave per row.
// ---------------------------------------------------------------------------
__global__ __launch_bounds__(256) void out_kernel(
    const float* __restrict__ h1, const float* __restrict__ w_out,
    const float* __restrict__ b_out, float* __restrict__ out)
{
    const int wave = threadIdx.x >> 6;
    const int lane = threadIdx.x & 63;
    const int b = blockIdx.x * 4 + wave;
    const float* row = h1 + (size_t)b * 512;
    float s = 0.f;
    #pragma unroll
    for (int i = 0; i < 8; ++i) {
        int k = lane + i * 64;
        s = fmaf(row[k], w_out[k], s);
    }
    #pragma unroll
    for (int off = 32; off; off >>= 1) s += __shfl_down(s, off, 64);
    if (lane == 0) out[b] = 1.f / (1.f + expf(-(s + b_out[0])));
}

// ---------------------------------------------------------------------------
extern "C" void kernel_launch(void* const* d_in, const int* in_sizes, int n_in,
                              void* d_out, int out_size, void* d_ws, size_t ws_size,
                              hipStream_t stream)
{
    const int*   x     = (const int*)  d_in[0];
    const float* emb   = (const float*)d_in[1];
    const float* w_c   = (const float*)d_in[2];
    const float* b_c   = (const float*)d_in[3];
    const float* g_c   = (const float*)d_in[4];
    const float* be_c  = (const float*)d_in[5];
    const float* w0    = (const float*)d_in[6];
    const float* b0    = (const float*)d_in[7];
    const float* g0    = (const float*)d_in[8];
    const float* be0   = (const float*)d_in[9];
    const float* w1    = (const float*)d_in[10];
    const float* b1    = (const float*)d_in[11];
    const float* g1    = (const float*)d_in[12];
    const float* be1   = (const float*)d_in[13];
    const float* w_out = (const float*)d_in[14];
    const float* b_out = (const float*)d_in[15];
    float* out = (float*)d_out;

    char* ws = (char*)d_ws;
    const size_t z_bytes = (size_t)B_SZ * FD * sizeof(float);        // 40.9 MB
    float* z  = (float*)ws;
    float* h0 = (float*)(ws + ((z_bytes + 255) & ~(size_t)255));     // 67.1 MB
    float* h1 = z;  // z is dead after GEMM0; reuse its space

    controller_select_kernel<<<B_SZ, 64, 0, stream>>>(x, emb, w_c, b_c, g_c, be_c, z);
    gemm_bn_relu_kernel<<<dim3(1024 / TN, B_SZ / TM), 256, 0, stream>>>(
        z, w0, b0, g0, be0, h0, B_SZ, 1024, FD);
    gemm_bn_relu_kernel<<<dim3(512 / TN, B_SZ / TM), 256, 0, stream>>>(
        h0, w1, b1, g1, be1, h1, B_SZ, 512, 1024);
    out_kernel<<<B_SZ / 4, 256, 0, stream>>>(h1, w_out, b_out, out);
}

// Round 2
// 311.459 us; speedup vs baseline: 2.5516x; 2.5516x over previous
//
#include <hip/hip_runtime.h>
#include <math.h>

#define B_SZ 16384
#define F_N 39
#define V_N 30000
#define D_N 16
#define K_SEL 20
#define FD 624     // F_N * D_N
#define KP0 640    // K of GEMM0 padded to multiple of 32
#define N0 1024
#define N1 512

typedef unsigned short u16;
typedef __attribute__((ext_vector_type(8))) short bf16x8;
typedef __attribute__((ext_vector_type(4))) float f32x4;

__device__ __forceinline__ u16 f2bf(float v) {
    union { float f; unsigned u; } x; x.f = v;
    unsigned r = x.u + 0x7fff + ((x.u >> 16) & 1);   // RNE
    return (u16)(r >> 16);
}

#define GLD16(gp, lp) __builtin_amdgcn_global_load_lds( \
    (const __attribute__((address_space(1))) unsigned int*)(gp), \
    (__attribute__((address_space(3))) unsigned int*)(lp), 16, 0, 0)

// ---------------------------------------------------------------------------
// transpose w_c [39][624] -> wct [624][39] for coalesced controller reads
// ---------------------------------------------------------------------------
__global__ void transpose_wc_kernel(const float* __restrict__ w_c,
                                    float* __restrict__ wct)
{
    int i = blockIdx.x * blockDim.x + threadIdx.x;
    if (i >= FD * F_N) return;
    int j = i / F_N, f = i - j * F_N;
    wct[i] = w_c[f * FD + j];
}

// ---------------------------------------------------------------------------
// fp32 [rows][K] -> bf16 [rows][Kp], zero-padded cols K..Kp
// ---------------------------------------------------------------------------
__global__ void convert_pad_kernel(const float* __restrict__ src,
                                   u16* __restrict__ dst, int rows, int K, int Kp)
{
    int i = blockIdx.x * blockDim.x + threadIdx.x;
    if (i >= rows * Kp) return;
    int r = i / Kp, c = i - r * Kp;
    float v = (c < K) ? src[r * K + c] : 0.f;
    dst[i] = f2bf(v);
}

// ---------------------------------------------------------------------------
// Kernel 1: gather + controller MLP + softmax + top-K mask + weight -> z bf16
// One wave per batch row. z[b, d*39+f] = sel(f) * score[f] * emb[b,f,d]
// ---------------------------------------------------------------------------
__global__ __launch_bounds__(64) void controller_select_kernel(
    const int* __restrict__ x, const float* __restrict__ emb_table,
    const float* __restrict__ wct, const float* __restrict__ b_c,
    const float* __restrict__ g_c, const float* __restrict__ be_c,
    u16* __restrict__ zb)
{
    __shared__ float flat[FD];   // flat[d*39+f]
    __shared__ float sc[F_N];
    __shared__ float wsel[F_N];
    __shared__ int   rowidx[F_N];

    const int b = blockIdx.x;
    const int t = threadIdx.x;

    if (t < F_N) rowidx[t] = x[b * F_N + t] + t * V_N;
    __syncthreads();

    const int fq = t >> 4;
    const int d  = t & 15;
    for (int fb = 0; fb < 40; fb += 4) {
        int f = fb + fq;
        if (f < F_N)
            flat[d * F_N + f] = emb_table[(size_t)rowidx[f] * D_N + d];
    }
    __syncthreads();

    const float rs = rsqrtf(1.0f + 1e-5f);
    if (t < F_N) {
        float s0 = 0.f, s1 = 0.f, s2 = 0.f, s3 = 0.f;
        #pragma unroll 4
        for (int j = 0; j < FD; j += 4) {
            s0 = fmaf(flat[j],     wct[(j)     * F_N + t], s0);
            s1 = fmaf(flat[j + 1], wct[(j + 1) * F_N + t], s1);
            s2 = fmaf(flat[j + 2], wct[(j + 2) * F_N + t], s2);
            s3 = fmaf(flat[j + 3], wct[(j + 3) * F_N + t], s3);
        }
        float s = (s0 + s1) + (s2 + s3) + b_c[t];
        s = g_c[t] * s * rs + be_c[t];
        sc[t] = fmaxf(s, 0.f);
    }
    __syncthreads();

    float mx = -1e30f;
    for (int f = 0; f < F_N; ++f) mx = fmaxf(mx, sc[f]);
    float sum = 0.f;
    for (int f = 0; f < F_N; ++f) sum += expf(sc[f] - mx);
    float mysc = (t < F_N) ? expf(sc[t] - mx) / sum : 0.f;
    __syncthreads();
    if (t < F_N) sc[t] = mysc;
    __syncthreads();

    if (t < F_N) {
        int rank = 0;
        for (int f = 0; f < F_N; ++f) {
            float o = sc[f];
            if (o > mysc || (o == mysc && f < t)) rank++;
        }
        wsel[t] = (rank < K_SEL) ? mysc : 0.f;
    }
    __syncthreads();

    u16* zrow = zb + (size_t)b * KP0;
    for (int j = t; j < KP0; j += 64) {
        float v = (j < FD) ? wsel[j % F_N] * flat[j] : 0.f;
        zrow[j] = f2bf(v);
    }
}

// ---------------------------------------------------------------------------
// MFMA GEMM: C[M,N] = relu(bn(A[M,Kp] @ W[N,Kp]^T + bias))
// 128x128 tile, 256 thr (4 waves, 2x2), BK=32, 16x16x32 bf16 MFMA,
// global_load_lds width-16 staging, XOR-swizzled LDS units.
// ---------------------------------------------------------------------------
template<int STORE_BF16>
__global__ __launch_bounds__(256) void gemm_mfma_bn_relu(
    const u16* __restrict__ A, const u16* __restrict__ W,
    const float* __restrict__ bias, const float* __restrict__ g,
    const float* __restrict__ be, void* __restrict__ Cout,
    int M, int N, int Kp)
{
    __shared__ __align__(16) u16 As[128 * 32];
    __shared__ __align__(16) u16 Bs[128 * 32];

    const int t    = threadIdx.x;
    const int wave = t >> 6;
    const int lane = t & 63;
    const int wm   = wave >> 1, wn = wave & 1;
    const int m0   = blockIdx.y * 128;
    const int n0   = blockIdx.x * 128;

    // staging: wave stages rows [wave*32, wave*32+32) of both tiles,
    // 2 instrs x 16 rows; lane i -> row base+(i>>2), global unit (i&3)^((i>>3)&3)
    const int lr    = lane >> 2;
    const int swz_u = (lane & 3) ^ ((lane >> 3) & 3);
    const u16* gA0 = A + (size_t)(m0 + wave * 32 + lr) * Kp + swz_u * 8;
    const u16* gA1 = gA0 + 16 * (size_t)Kp;
    const u16* gB0 = W + (size_t)(n0 + wave * 32 + lr) * Kp + swz_u * 8;
    const u16* gB1 = gB0 + 16 * (size_t)Kp;
    u16* lA0 = &As[(wave * 32)      * 32];
    u16* lA1 = &As[(wave * 32 + 16) * 32];
    u16* lB0 = &Bs[(wave * 32)      * 32];
    u16* lB1 = &Bs[(wave * 32 + 16) * 32];

    const int q    = lane >> 4;
    const int lr16 = lane & 15;

    // frag LDS short-indices: logical (row r, unit q) -> phys unit q^((r>>1)&3)
    int aoff[4], boff[4];
    #pragma unroll
    for (int i = 0; i < 4; ++i) {
        int ra = wm * 64 + i * 16 + lr16;
        aoff[i] = ra * 32 + ((q ^ ((ra >> 1) & 3)) * 8);
        int rb = wn * 64 + i * 16 + lr16;
        boff[i] = rb * 32 + ((q ^ ((rb >> 1) & 3)) * 8);
    }

    f32x4 acc[4][4] = {};

    for (int k0 = 0; k0 < Kp; k0 += 32) {
        GLD16(gA0, lA0); GLD16(gA1, lA1);
        GLD16(gB0, lB0); GLD16(gB1, lB1);
        gA0 += 32; gA1 += 32; gB0 += 32; gB1 += 32;
        __syncthreads();   // drains vmcnt, LDS tile visible

        bf16x8 af[4], bfr[4];
        #pragma unroll
        for (int i = 0; i < 4; ++i) af[i]  = *(const bf16x8*)&As[aoff[i]];
        #pragma unroll
        for (int j = 0; j < 4; ++j) bfr[j] = *(const bf16x8*)&Bs[boff[j]];

        #pragma unroll
        for (int i = 0; i < 4; ++i)
            #pragma unroll
            for (int j = 0; j < 4; ++j)
                acc[i][j] = __builtin_amdgcn_mfma_f32_16x16x32_bf16(
                    af[i], bfr[j], acc[i][j], 0, 0, 0);
        __syncthreads();   // protect LDS before next staging
    }

    const float rs = rsqrtf(1.0f + 1e-5f);
    #pragma unroll
    for (int j = 0; j < 4; ++j) {
        const int n = n0 + wn * 64 + j * 16 + lr16;
        const float bn_g = g[n] * rs;
        const float bn_b = be[n];
        const float bi   = bias[n];
        #pragma unroll
        for (int i = 0; i < 4; ++i) {
            const int mbase = m0 + wm * 64 + i * 16 + q * 4;
            #pragma unroll
            for (int r = 0; r < 4; ++r) {
                float v = acc[i][j][r] + bi;
                v = fmaxf(fmaf(bn_g, v, bn_b), 0.f);
                const size_t off = (size_t)(mbase + r) * N + n;
                if (STORE_BF16) ((u16*)Cout)[off] = f2bf(v);
                else            ((float*)Cout)[off] = v;
            }
        }
    }
}

// ---------------------------------------------------------------------------
// out[b] = sigmoid(dot(h1[b,:512], w_out) + b_out); one wave per row
// ---------------------------------------------------------------------------
__global__ __launch_bounds__(256) void out_kernel(
    const float* __restrict__ h1, const float* __restrict__ w_out,
    const float* __restrict__ b_out, float* __restrict__ out)
{
    const int wave = threadIdx.x >> 6;
    const int lane = threadIdx.x & 63;
    const int b = blockIdx.x * 4 + wave;
    const float* row = h1 + (size_t)b * 512;
    float s = 0.f;
    #pragma unroll
    for (int i = 0; i < 8; ++i) {
        int k = lane + i * 64;
        s = fmaf(row[k], w_out[k], s);
    }
    #pragma unroll
    for (int off = 32; off; off >>= 1) s += __shfl_down(s, off, 64);
    if (lane == 0) out[b] = 1.f / (1.f + expf(-(s + b_out[0])));
}

// ---------------------------------------------------------------------------
extern "C" void kernel_launch(void* const* d_in, const int* in_sizes, int n_in,
                              void* d_out, int out_size, void* d_ws, size_t ws_size,
                              hipStream_t stream)
{
    const int*   x     = (const int*)  d_in[0];
    const float* emb   = (const float*)d_in[1];
    const float* w_c   = (const float*)d_in[2];
    const float* b_c   = (const float*)d_in[3];
    const float* g_c   = (const float*)d_in[4];
    const float* be_c  = (const float*)d_in[5];
    const float* w0    = (const float*)d_in[6];
    const float* b0    = (const float*)d_in[7];
    const float* g0    = (const float*)d_in[8];
    const float* be0   = (const float*)d_in[9];
    const float* w1    = (const float*)d_in[10];
    const float* b1    = (const float*)d_in[11];
    const float* g1    = (const float*)d_in[12];
    const float* be1   = (const float*)d_in[13];
    const float* w_out = (const float*)d_in[14];
    const float* b_out = (const float*)d_in[15];
    float* out = (float*)d_out;

    // workspace layout (bytes, all 16B aligned)
    u16*   zb  = (u16*)d_ws;                        // 16384*640*2  = 20.97 MB
    u16*   w0b = zb  + (size_t)B_SZ * KP0;          // 1024*640*2   =  1.31 MB
    u16*   h0b = w0b + (size_t)N0 * KP0;            // 16384*1024*2 = 33.55 MB
    u16*   w1b = h0b + (size_t)B_SZ * N0;           // 512*1024*2   =  1.05 MB
    float* h1  = (float*)(w1b + (size_t)N1 * N0);   // 16384*512*4  = 33.55 MB
    float* wct = h1 + (size_t)B_SZ * N1;            // 624*39*4     =  0.10 MB

    transpose_wc_kernel<<<(FD * F_N + 255) / 256, 256, 0, stream>>>(w_c, wct);
    convert_pad_kernel<<<(N0 * KP0 + 255) / 256, 256, 0, stream>>>(w0, w0b, N0, FD, KP0);
    convert_pad_kernel<<<(N1 * N0 + 255) / 256, 256, 0, stream>>>(w1, w1b, N1, N0, N0);

    controller_select_kernel<<<B_SZ, 64, 0, stream>>>(x, emb, wct, b_c, g_c, be_c, zb);

    gemm_mfma_bn_relu<1><<<dim3(N0 / 128, B_SZ / 128), 256, 0, stream>>>(
        zb, w0b, b0, g0, be0, h0b, B_SZ, N0, KP0);
    gemm_mfma_bn_relu<0><<<dim3(N1 / 128, B_SZ / 128), 256, 0, stream>>>(
        h0b, w1b, b1, g1, be1, h1, B_SZ, N1, N0);

    out_kernel<<<B_SZ / 4, 256, 0, stream>>>(h1, w_out, b_out, out);
}

// Round 3
// 276.896 us; speedup vs baseline: 2.8701x; 1.1248x over previous
//
#include <hip/hip_runtime.h>
#include <math.h>

#define B_SZ 16384
#define F_N 39
#define V_N 30000
#define D_N 16
#define K_SEL 20
#define FD 624     // F_N * D_N
#define KP0 640    // K of controller/GEMM0 padded to multiple of 32
#define NC 128     // controller GEMM padded N
#define N0 1024
#define N1 512

typedef unsigned short u16;
typedef __attribute__((ext_vector_type(8))) short bf16x8;
typedef __attribute__((ext_vector_type(4))) float f32x4;
typedef __attribute__((ext_vector_type(4))) unsigned short u16x4;

__device__ __forceinline__ u16 f2bf(float v) {
    union { float f; unsigned u; } x; x.f = v;
    unsigned r = x.u + 0x7fff + ((x.u >> 16) & 1);   // RNE
    return (u16)(r >> 16);
}
__device__ __forceinline__ float bf2f(u16 v) {
    union { unsigned u; float f; } x; x.u = ((unsigned)v) << 16;
    return x.f;
}

#define GLD16(gp, lp) __builtin_amdgcn_global_load_lds( \
    (const __attribute__((address_space(1))) unsigned int*)(gp), \
    (__attribute__((address_space(3))) unsigned int*)(lp), 16, 0, 0)

// ---------------------------------------------------------------------------
// Prep: w0/w1 fp32 -> bf16, zero-padded K
// ---------------------------------------------------------------------------
__global__ void convert_pad_kernel(const float* __restrict__ src,
                                   u16* __restrict__ dst, int rows, int K, int Kp)
{
    int i = blockIdx.x * blockDim.x + threadIdx.x;
    if (i >= rows * Kp) return;
    int r = i / Kp, c = i - r * Kp;
    float v = (c < K) ? src[r * K + c] : 0.f;
    dst[i] = f2bf(v);
}

// ---------------------------------------------------------------------------
// Prep: wcb[n][f*16+d] = w_c[n][d*39+f] (n<39), zero pad to [128][640] bf16
// ---------------------------------------------------------------------------
__global__ void prep_wc_kernel(const float* __restrict__ w_c, u16* __restrict__ wcb)
{
    int i = blockIdx.x * blockDim.x + threadIdx.x;
    if (i >= NC * KP0) return;
    int n = i / KP0, kk = i - n * KP0;
    float v = 0.f;
    if (n < F_N && kk < FD) {
        int f = kk >> 4, d = kk & 15;
        v = w_c[n * FD + d * F_N + f];
    }
    wcb[i] = f2bf(v);
}

// ---------------------------------------------------------------------------
// Prep: pad controller bn params 39 -> 128 (zeros)
// ---------------------------------------------------------------------------
__global__ void pad_params_kernel(const float* __restrict__ b_c,
                                  const float* __restrict__ g_c,
                                  const float* __restrict__ be_c,
                                  float* __restrict__ bp, float* __restrict__ gp,
                                  float* __restrict__ bep)
{
    int n = threadIdx.x;
    bp[n]  = (n < F_N) ? b_c[n]  : 0.f;
    gp[n]  = (n < F_N) ? g_c[n]  : 0.f;
    bep[n] = (n < F_N) ? be_c[n] : 0.f;
}

// ---------------------------------------------------------------------------
// Gather: flatb[b][f*16+d] = bf16(emb_table[x[b,f]+f*V][d]); cols 624..639 = 0
// 4 lanes per (b,f) row, 64 rows per 256-thr block. Pure memory, max MLP.
// ---------------------------------------------------------------------------
#define GROWS_BLK 64
#define GBLOCKS (B_SZ * F_N / GROWS_BLK)   // 9984
__global__ __launch_bounds__(256) void gather_kernel(
    const int* __restrict__ x, const float* __restrict__ emb_table,
    u16* __restrict__ flatb)
{
    const int t = threadIdx.x;
    if (blockIdx.x >= GBLOCKS) {           // tail-zero blocks
        int b = (blockIdx.x - GBLOCKS) * 256 + t;
        float4 zz = {0.f, 0.f, 0.f, 0.f};
        float4* p = (float4*)(flatb + (size_t)b * KP0 + FD);
        p[0] = zz; p[1] = zz;              // 16 u16 zeros
        return;
    }
    const int r = blockIdx.x * GROWS_BLK + (t >> 2);   // (b,f) row id
    const int lane4 = t & 3;
    const int b = r / F_N;
    const int f = r - b * F_N;
    const int row = x[r] + f * V_N;
    const float4 v = *(const float4*)(emb_table + (size_t)row * D_N + lane4 * 4);
    u16x4 o = { f2bf(v.x), f2bf(v.y), f2bf(v.z), f2bf(v.w) };
    *(u16x4*)(flatb + (size_t)b * KP0 + f * D_N + lane4 * 4) = o;
}

// ---------------------------------------------------------------------------
// MFMA GEMM: C[M,N] = relu(bn(A[M,Kp] @ W[N,Kp]^T + bias))
// 128x128 tile, 256 thr (4 waves, 2x2), BK=32, 16x16x32 bf16 MFMA,
// global_load_lds width-16 staging, XOR-swizzled LDS units.
// ---------------------------------------------------------------------------
template<int STORE_BF16>
__global__ __launch_bounds__(256) void gemm_mfma_bn_relu(
    const u16* __restrict__ A, const u16* __restrict__ W,
    const float* __restrict__ bias, const float* __restrict__ g,
    const float* __restrict__ be, void* __restrict__ Cout,
    int M, int N, int Kp)
{
    __shared__ __align__(16) u16 As[128 * 32];
    __shared__ __align__(16) u16 Bs[128 * 32];

    const int t    = threadIdx.x;
    const int wave = t >> 6;
    const int lane = t & 63;
    const int wm   = wave >> 1, wn = wave & 1;
    const int m0   = blockIdx.y * 128;
    const int n0   = blockIdx.x * 128;

    const int lr    = lane >> 2;
    const int swz_u = (lane & 3) ^ ((lane >> 3) & 3);
    const u16* gA0 = A + (size_t)(m0 + wave * 32 + lr) * Kp + swz_u * 8;
    const u16* gA1 = gA0 + 16 * (size_t)Kp;
    const u16* gB0 = W + (size_t)(n0 + wave * 32 + lr) * Kp + swz_u * 8;
    const u16* gB1 = gB0 + 16 * (size_t)Kp;
    u16* lA0 = &As[(wave * 32)      * 32];
    u16* lA1 = &As[(wave * 32 + 16) * 32];
    u16* lB0 = &Bs[(wave * 32)      * 32];
    u16* lB1 = &Bs[(wave * 32 + 16) * 32];

    const int q    = lane >> 4;
    const int lr16 = lane & 15;

    int aoff[4], boff[4];
    #pragma unroll
    for (int i = 0; i < 4; ++i) {
        int ra = wm * 64 + i * 16 + lr16;
        aoff[i] = ra * 32 + ((q ^ ((ra >> 1) & 3)) * 8);
        int rb = wn * 64 + i * 16 + lr16;
        boff[i] = rb * 32 + ((q ^ ((rb >> 1) & 3)) * 8);
    }

    f32x4 acc[4][4] = {};

    for (int k0 = 0; k0 < Kp; k0 += 32) {
        GLD16(gA0, lA0); GLD16(gA1, lA1);
        GLD16(gB0, lB0); GLD16(gB1, lB1);
        gA0 += 32; gA1 += 32; gB0 += 32; gB1 += 32;
        __syncthreads();

        bf16x8 af[4], bfr[4];
        #pragma unroll
        for (int i = 0; i < 4; ++i) af[i]  = *(const bf16x8*)&As[aoff[i]];
        #pragma unroll
        for (int j = 0; j < 4; ++j) bfr[j] = *(const bf16x8*)&Bs[boff[j]];

        #pragma unroll
        for (int i = 0; i < 4; ++i)
            #pragma unroll
            for (int j = 0; j < 4; ++j)
                acc[i][j] = __builtin_amdgcn_mfma_f32_16x16x32_bf16(
                    af[i], bfr[j], acc[i][j], 0, 0, 0);
        __syncthreads();
    }

    const float rs = rsqrtf(1.0f + 1e-5f);
    #pragma unroll
    for (int j = 0; j < 4; ++j) {
        const int n = n0 + wn * 64 + j * 16 + lr16;
        const float bn_g = g[n] * rs;
        const float bn_b = be[n];
        const float bi   = bias[n];
        #pragma unroll
        for (int i = 0; i < 4; ++i) {
            const int mbase = m0 + wm * 64 + i * 16 + q * 4;
            #pragma unroll
            for (int r = 0; r < 4; ++r) {
                float v = acc[i][j][r] + bi;
                v = fmaxf(fmaf(bn_g, v, bn_b), 0.f);
                const size_t off = (size_t)(mbase + r) * N + n;
                if (STORE_BF16) ((u16*)Cout)[off] = f2bf(v);
                else            ((float*)Cout)[off] = v;
            }
        }
    }
}

// ---------------------------------------------------------------------------
// Select+scale: softmax over hc[b,:39], top-K mask (lax.top_k tie-break),
// zb[b][d*39+f] = wsel[f] * flatb[b][f*16+d].  4 rows / 256-thr block.
// ---------------------------------------------------------------------------
__global__ __launch_bounds__(256) void select_scale_kernel(
    const float* __restrict__ hc, const u16* __restrict__ flatb,
    u16* __restrict__ zb)
{
    __shared__ float sc[4][F_N];
    __shared__ float wsel[4][F_N];
    __shared__ float fz[4][FD];

    const int wave = threadIdx.x >> 6;
    const int lane = threadIdx.x & 63;
    const int b = blockIdx.x * 4 + wave;

    if (lane < F_N) sc[wave][lane] = hc[(size_t)b * NC + lane];
    __syncthreads();

    float mx = -1e30f;
    for (int f = 0; f < F_N; ++f) mx = fmaxf(mx, sc[wave][f]);
    float sum = 0.f;
    for (int f = 0; f < F_N; ++f) sum += expf(sc[wave][f] - mx);
    float mysc = (lane < F_N) ? expf(sc[wave][lane] - mx) / sum : 0.f;
    __syncthreads();
    if (lane < F_N) sc[wave][lane] = mysc;
    __syncthreads();

    if (lane < F_N) {
        int rank = 0;
        for (int f = 0; f < F_N; ++f) {
            float o = sc[wave][f];
            if (o > mysc || (o == mysc && f < lane)) rank++;
        }
        wsel[wave][lane] = (rank < K_SEL) ? mysc : 0.f;
    }
    __syncthreads();

    // permute [f*16+d] -> [d*39+f] with scale, via LDS
    const u16* frow = flatb + (size_t)b * KP0;
    for (int jj = lane; jj < FD; jj += 64) {
        int f = jj >> 4, d = jj & 15;
        fz[wave][d * F_N + f] = bf2f(frow[jj]) * wsel[wave][f];
    }
    __syncthreads();

    u16* zrow = zb + (size_t)b * KP0;
    for (int j = lane; j < KP0; j += 64)
        zrow[j] = f2bf(j < FD ? fz[wave][j] : 0.f);
}

// ---------------------------------------------------------------------------
// out[b] = sigmoid(dot(h1b[b,:512], w_out) + b_out); one wave per row
// ---------------------------------------------------------------------------
__global__ __launch_bounds__(256) void out_kernel(
    const u16* __restrict__ h1b, const float* __restrict__ w_out,
    const float* __restrict__ b_out, float* __restrict__ out)
{
    const int wave = threadIdx.x >> 6;
    const int lane = threadIdx.x & 63;
    const int b = blockIdx.x * 4 + wave;
    const u16* row = h1b + (size_t)b * N1;
    float s = 0.f;
    #pragma unroll
    for (int i = 0; i < 8; ++i) {
        int k = lane + i * 64;
        s = fmaf(bf2f(row[k]), w_out[k], s);
    }
    #pragma unroll
    for (int off = 32; off; off >>= 1) s += __shfl_down(s, off, 64);
    if (lane == 0) out[b] = 1.f / (1.f + expf(-(s + b_out[0])));
}

// ---------------------------------------------------------------------------
extern "C" void kernel_launch(void* const* d_in, const int* in_sizes, int n_in,
                              void* d_out, int out_size, void* d_ws, size_t ws_size,
                              hipStream_t stream)
{
    const int*   x     = (const int*)  d_in[0];
    const float* emb   = (const float*)d_in[1];
    const float* w_c   = (const float*)d_in[2];
    const float* b_c   = (const float*)d_in[3];
    const float* g_c   = (const float*)d_in[4];
    const float* be_c  = (const float*)d_in[5];
    const float* w0    = (const float*)d_in[6];
    const float* b0    = (const float*)d_in[7];
    const float* g0    = (const float*)d_in[8];
    const float* be0   = (const float*)d_in[9];
    const float* w1    = (const float*)d_in[10];
    const float* b1    = (const float*)d_in[11];
    const float* g1    = (const float*)d_in[12];
    const float* be1   = (const float*)d_in[13];
    const float* w_out = (const float*)d_in[14];
    const float* b_out = (const float*)d_in[15];
    float* out = (float*)d_out;

    // workspace layout (16B aligned, ~103 MB total; round-0 needed 108 MB so ws fits)
    u16*   flatb = (u16*)d_ws;                          // 16384*640*2  = 20.97 MB
    u16*   zb    = flatb + (size_t)B_SZ * KP0;          // 20.97 MB
    u16*   w0b   = zb    + (size_t)B_SZ * KP0;          // 1.31 MB
    u16*   h0b   = w0b   + (size_t)N0 * KP0;            // 33.55 MB
    u16*   w1b   = h0b   + (size_t)B_SZ * N0;           // 1.05 MB
    u16*   h1b   = w1b   + (size_t)N1 * N0;             // 16.78 MB
    u16*   wcb   = h1b   + (size_t)B_SZ * N1;           // 0.16 MB
    float* hc    = (float*)(wcb + (size_t)NC * KP0);    // 16384*128*4 = 8.39 MB
    float* bcp   = hc  + (size_t)B_SZ * NC;
    float* gcp   = bcp + NC;
    float* becp  = gcp + NC;

    pad_params_kernel<<<1, NC, 0, stream>>>(b_c, g_c, be_c, bcp, gcp, becp);
    prep_wc_kernel<<<(NC * KP0 + 255) / 256, 256, 0, stream>>>(w_c, wcb);
    convert_pad_kernel<<<(N0 * KP0 + 255) / 256, 256, 0, stream>>>(w0, w0b, N0, FD, KP0);
    convert_pad_kernel<<<(N1 * N0 + 255) / 256, 256, 0, stream>>>(w1, w1b, N1, N0, N0);

    gather_kernel<<<GBLOCKS + B_SZ / 256, 256, 0, stream>>>(x, emb, flatb);

    gemm_mfma_bn_relu<0><<<dim3(NC / 128, B_SZ / 128), 256, 0, stream>>>(
        flatb, wcb, bcp, gcp, becp, hc, B_SZ, NC, KP0);

    select_scale_kernel<<<B_SZ / 4, 256, 0, stream>>>(hc, flatb, zb);

    gemm_mfma_bn_relu<1><<<dim3(N0 / 128, B_SZ / 128), 256, 0, stream>>>(
        zb, w0b, b0, g0, be0, h0b, B_SZ, N0, KP0);
    gemm_mfma_bn_relu<1><<<dim3(N1 / 128, B_SZ / 128), 256, 0, stream>>>(
        h0b, w1b, b1, g1, be1, h1b, B_SZ, N1, N0);

    out_kernel<<<B_SZ / 4, 256, 0, stream>>>(h1b, w_out, b_out, out);
}

// Round 4
// 255.529 us; speedup vs baseline: 3.1101x; 1.0836x over previous
//
#include <hip/hip_runtime.h>
#include <math.h>

#define B_SZ 16384
#define F_N 39
#define V_N 30000
#define D_N 16
#define K_SEL 20
#define FD 624     // F_N * D_N
#define KP0 640    // controller/GEMM0 K padded to multiple of 32
#define NCP 64     // controller GEMM padded N (>= 39)
#define N0 1024
#define N1 512
#define WSL 40     // wsel row stride

typedef unsigned short u16;
typedef __attribute__((ext_vector_type(8))) short bf16x8;
typedef __attribute__((ext_vector_type(4))) float f32x4;
typedef __attribute__((ext_vector_type(4))) unsigned short u16x4;

__device__ __forceinline__ u16 f2bf(float v) {
    union { float f; unsigned u; } x; x.f = v;
    unsigned r = x.u + 0x7fff + ((x.u >> 16) & 1);   // RNE
    return (u16)(r >> 16);
}
__device__ __forceinline__ float bf2f(u16 v) {
    union { unsigned u; float f; } x; x.u = ((unsigned)v) << 16;
    return x.f;
}

#define GLD16(gp, lp) __builtin_amdgcn_global_load_lds( \
    (const __attribute__((address_space(1))) unsigned int*)(gp), \
    (__attribute__((address_space(3))) unsigned int*)(lp), 16, 0, 0)

// ---------------------------------------------------------------------------
// Prep kernels
// ---------------------------------------------------------------------------
// w1 fp32 -> bf16 (no permute; k-order = h0 col order)
__global__ void convert_kernel(const float* __restrict__ src, u16* __restrict__ dst,
                               int n_el)
{
    int i = blockIdx.x * blockDim.x + threadIdx.x;
    if (i < n_el) dst[i] = f2bf(src[i]);
}

// w0p[n][f*16+d] = bf16(w0[n][d*39+f]), zero-pad cols 624..639
__global__ void prep_w0_kernel(const float* __restrict__ w0, u16* __restrict__ w0p)
{
    int i = blockIdx.x * blockDim.x + threadIdx.x;
    if (i >= N0 * KP0) return;
    int n = i / KP0, kk = i - n * KP0;
    float v = 0.f;
    if (kk < FD) {
        int f = kk >> 4, d = kk & 15;
        v = w0[n * FD + d * F_N + f];
    }
    w0p[i] = f2bf(v);
}

// wcb[n][f*16+d] = bf16(w_c[n][d*39+f]), zero-pad n to 64 rows, k to 640
__global__ void prep_wc_kernel(const float* __restrict__ w_c, u16* __restrict__ wcb)
{
    int i = blockIdx.x * blockDim.x + threadIdx.x;
    if (i >= NCP * KP0) return;
    int n = i / KP0, kk = i - n * KP0;
    float v = 0.f;
    if (n < F_N && kk < FD) {
        int f = kk >> 4, d = kk & 15;
        v = w_c[n * FD + d * F_N + f];
    }
    wcb[i] = f2bf(v);
}

// pad controller bn params 39 -> 64
__global__ void pad_params_kernel(const float* __restrict__ b_c,
                                  const float* __restrict__ g_c,
                                  const float* __restrict__ be_c,
                                  float* __restrict__ bp, float* __restrict__ gp,
                                  float* __restrict__ bep)
{
    int n = threadIdx.x;
    bp[n]  = (n < F_N) ? b_c[n]  : 0.f;
    gp[n]  = (n < F_N) ? g_c[n]  : 0.f;
    bep[n] = (n < F_N) ? be_c[n] : 0.f;
}

// ---------------------------------------------------------------------------
// Gather: flatb[b][f*16+d] = bf16(emb_table[x[b,f]+f*V][d]); cols 624..639 = 0
// ---------------------------------------------------------------------------
#define GROWS_BLK 64
#define GBLOCKS (B_SZ * F_N / GROWS_BLK)   // 9984
__global__ __launch_bounds__(256) void gather_kernel(
    const int* __restrict__ x, const float* __restrict__ emb_table,
    u16* __restrict__ flatb)
{
    const int t = threadIdx.x;
    if (blockIdx.x >= GBLOCKS) {           // tail-zero blocks
        int b = (blockIdx.x - GBLOCKS) * 256 + t;
        float4 zz = {0.f, 0.f, 0.f, 0.f};
        float4* p = (float4*)(flatb + (size_t)b * KP0 + FD);
        p[0] = zz; p[1] = zz;
        return;
    }
    const int r = blockIdx.x * GROWS_BLK + (t >> 2);
    const int lane4 = t & 3;
    const int b = r / F_N;
    const int f = r - b * F_N;
    const int row = x[r] + f * V_N;
    const float4 v = *(const float4*)(emb_table + (size_t)row * D_N + lane4 * 4);
    u16x4 o = { f2bf(v.x), f2bf(v.y), f2bf(v.z), f2bf(v.w) };
    *(u16x4*)(flatb + (size_t)b * KP0 + f * D_N + lane4 * 4) = o;
}

// ---------------------------------------------------------------------------
// Controller GEMM + softmax + top-K fused. TM=64, TN=64, BK=32, 256 thr.
// hc[b][n] = relu(bn(flatb[b,:] . wcb[n,:])), then per-row softmax over n<39,
// top-K rank mask -> wsel[b][f].
// ---------------------------------------------------------------------------
__global__ __launch_bounds__(256) void controller_gemm_select_kernel(
    const u16* __restrict__ A, const u16* __restrict__ W,
    const float* __restrict__ bias, const float* __restrict__ g,
    const float* __restrict__ be, float* __restrict__ wsel)
{
    __shared__ __align__(16) u16 As[64 * 32];
    __shared__ __align__(16) u16 Bs[64 * 32];
    __shared__ float vv[64][65];

    const int t    = threadIdx.x;
    const int wave = t >> 6;
    const int lane = t & 63;
    const int m0   = blockIdx.x * 64;

    // staging: wave w stages A rows w*16..+16 and B rows w*16..+16 (1 GLD each)
    const int lr    = lane >> 2;
    const int swz_u = (lane & 3) ^ ((lane >> 3) & 3);
    const u16* gA = A + (size_t)(m0 + wave * 16 + lr) * KP0 + swz_u * 8;
    const u16* gB = W + (size_t)(wave * 16 + lr) * KP0 + swz_u * 8;
    u16* lA = &As[(wave * 16) * 32];
    u16* lB = &Bs[(wave * 16) * 32];

    const int q    = lane >> 4;
    const int lr16 = lane & 15;

    const int ra = wave * 16 + lr16;
    const int aoff = ra * 32 + ((q ^ ((ra >> 1) & 3)) * 8);
    int boff[4];
    #pragma unroll
    for (int j = 0; j < 4; ++j) {
        int rb = j * 16 + lr16;
        boff[j] = rb * 32 + ((q ^ ((rb >> 1) & 3)) * 8);
    }

    f32x4 acc[4] = {};

    for (int k0 = 0; k0 < KP0; k0 += 32) {
        GLD16(gA, lA); GLD16(gB, lB);
        gA += 32; gB += 32;
        __syncthreads();
        bf16x8 af = *(const bf16x8*)&As[aoff];
        bf16x8 bfr[4];
        #pragma unroll
        for (int j = 0; j < 4; ++j) bfr[j] = *(const bf16x8*)&Bs[boff[j]];
        #pragma unroll
        for (int j = 0; j < 4; ++j)
            acc[j] = __builtin_amdgcn_mfma_f32_16x16x32_bf16(af, bfr[j], acc[j], 0, 0, 0);
        __syncthreads();
    }

    // bn + relu -> vv[row][col]
    const float rs = rsqrtf(1.0f + 1e-5f);
    #pragma unroll
    for (int j = 0; j < 4; ++j) {
        const int n = j * 16 + lr16;
        const float bn_g = g[n] * rs;
        const float bn_b = be[n];
        const float bi   = bias[n];
        #pragma unroll
        for (int r = 0; r < 4; ++r) {
            float v = acc[j][r] + bi;
            vv[wave * 16 + q * 4 + r][n] = fmaxf(fmaf(bn_g, v, bn_b), 0.f);
        }
    }
    __syncthreads();

    // softmax + top-K rank per row (threads 0..63, row = t)
    if (t < 64) {
        float rv[F_N];
        #pragma unroll
        for (int f = 0; f < F_N; ++f) rv[f] = vv[t][f];
        float mx = rv[0];
        #pragma unroll
        for (int f = 1; f < F_N; ++f) mx = fmaxf(mx, rv[f]);
        float sum = 0.f;
        #pragma unroll
        for (int f = 0; f < F_N; ++f) { rv[f] = expf(rv[f] - mx); sum += rv[f]; }
        const float inv = 1.f / sum;
        float* wrow = wsel + (size_t)(m0 + t) * WSL;
        #pragma unroll
        for (int f = 0; f < F_N; ++f) {
            int rank = 0;
            #pragma unroll
            for (int gg = 0; gg < F_N; ++gg)
                rank += (rv[gg] > rv[f] || (rv[gg] == rv[f] && gg < f)) ? 1 : 0;
            wrow[f] = (rank < K_SEL) ? rv[f] * inv : 0.f;
        }
    }
}

// ---------------------------------------------------------------------------
// Select-scale (streaming): zb[b][kk] = bf16(flatb[b][kk] * wsel[b][kk>>4])
// 8 u16 per thread; cols 624..639 zero.
// ---------------------------------------------------------------------------
__global__ __launch_bounds__(256) void select_scale_kernel(
    const u16* __restrict__ flatb, const float* __restrict__ wsel,
    u16* __restrict__ zb)
{
    const int i = blockIdx.x * blockDim.x + threadIdx.x;   // group of 8
    const int b = i / (KP0 / 8);
    const int kk = (i - b * (KP0 / 8)) * 8;
    u16x4 o0 = {0, 0, 0, 0}, o1 = {0, 0, 0, 0};
    if (kk < FD) {
        const float s = wsel[(size_t)b * WSL + (kk >> 4)];
        const u16x4* src = (const u16x4*)(flatb + (size_t)b * KP0 + kk);
        u16x4 a0 = src[0], a1 = src[1];
        o0 = { f2bf(bf2f(a0.x) * s), f2bf(bf2f(a0.y) * s),
               f2bf(bf2f(a0.z) * s), f2bf(bf2f(a0.w) * s) };
        o1 = { f2bf(bf2f(a1.x) * s), f2bf(bf2f(a1.y) * s),
               f2bf(bf2f(a1.z) * s), f2bf(bf2f(a1.w) * s) };
    }
    u16x4* dst = (u16x4*)(zb + (size_t)b * KP0 + kk);
    dst[0] = o0; dst[1] = o1;
}

// ---------------------------------------------------------------------------
// MFMA GEMM: C[M,N] = relu(bn(A[M,Kp] @ W[N,Kp]^T + bias)); 128x128 tile.
// M-panel on blockIdx.x (fastest) -> XCD-local A reuse.
// ---------------------------------------------------------------------------
template<int STORE_BF16>
__global__ __launch_bounds__(256) void gemm_mfma_bn_relu(
    const u16* __restrict__ A, const u16* __restrict__ W,
    const float* __restrict__ bias, const float* __restrict__ g,
    const float* __restrict__ be, void* __restrict__ Cout,
    int M, int N, int Kp)
{
    __shared__ __align__(16) u16 As[128 * 32];
    __shared__ __align__(16) u16 Bs[128 * 32];

    const int t    = threadIdx.x;
    const int wave = t >> 6;
    const int lane = t & 63;
    const int wm   = wave >> 1, wn = wave & 1;
    const int m0   = blockIdx.x * 128;   // M fastest -> same-XCD panel locality
    const int n0   = blockIdx.y * 128;

    const int lr    = lane >> 2;
    const int swz_u = (lane & 3) ^ ((lane >> 3) & 3);
    const u16* gA0 = A + (size_t)(m0 + wave * 32 + lr) * Kp + swz_u * 8;
    const u16* gA1 = gA0 + 16 * (size_t)Kp;
    const u16* gB0 = W + (size_t)(n0 + wave * 32 + lr) * Kp + swz_u * 8;
    const u16* gB1 = gB0 + 16 * (size_t)Kp;
    u16* lA0 = &As[(wave * 32)      * 32];
    u16* lA1 = &As[(wave * 32 + 16) * 32];
    u16* lB0 = &Bs[(wave * 32)      * 32];
    u16* lB1 = &Bs[(wave * 32 + 16) * 32];

    const int q    = lane >> 4;
    const int lr16 = lane & 15;

    int aoff[4], boff[4];
    #pragma unroll
    for (int i = 0; i < 4; ++i) {
        int ra = wm * 64 + i * 16 + lr16;
        aoff[i] = ra * 32 + ((q ^ ((ra >> 1) & 3)) * 8);
        int rb = wn * 64 + i * 16 + lr16;
        boff[i] = rb * 32 + ((q ^ ((rb >> 1) & 3)) * 8);
    }

    f32x4 acc[4][4] = {};

    for (int k0 = 0; k0 < Kp; k0 += 32) {
        GLD16(gA0, lA0); GLD16(gA1, lA1);
        GLD16(gB0, lB0); GLD16(gB1, lB1);
        gA0 += 32; gA1 += 32; gB0 += 32; gB1 += 32;
        __syncthreads();

        bf16x8 af[4], bfr[4];
        #pragma unroll
        for (int i = 0; i < 4; ++i) af[i]  = *(const bf16x8*)&As[aoff[i]];
        #pragma unroll
        for (int j = 0; j < 4; ++j) bfr[j] = *(const bf16x8*)&Bs[boff[j]];

        #pragma unroll
        for (int i = 0; i < 4; ++i)
            #pragma unroll
            for (int j = 0; j < 4; ++j)
                acc[i][j] = __builtin_amdgcn_mfma_f32_16x16x32_bf16(
                    af[i], bfr[j], acc[i][j], 0, 0, 0);
        __syncthreads();
    }

    const float rs = rsqrtf(1.0f + 1e-5f);
    #pragma unroll
    for (int j = 0; j < 4; ++j) {
        const int n = n0 + wn * 64 + j * 16 + lr16;
        const float bn_g = g[n] * rs;
        const float bn_b = be[n];
        const float bi   = bias[n];
        #pragma unroll
        for (int i = 0; i < 4; ++i) {
            const int mbase = m0 + wm * 64 + i * 16 + q * 4;
            #pragma unroll
            for (int r = 0; r < 4; ++r) {
                float v = acc[i][j][r] + bi;
                v = fmaxf(fmaf(bn_g, v, bn_b), 0.f);
                const size_t off = (size_t)(mbase + r) * N + n;
                if (STORE_BF16) ((u16*)Cout)[off] = f2bf(v);
                else            ((float*)Cout)[off] = v;
            }
        }
    }
}

// ---------------------------------------------------------------------------
// out[b] = sigmoid(dot(h1b[b,:512], w_out) + b_out); one wave per row
// ---------------------------------------------------------------------------
__global__ __launch_bounds__(256) void out_kernel(
    const u16* __restrict__ h1b, const float* __restrict__ w_out,
    const float* __restrict__ b_out, float* __restrict__ out)
{
    const int wave = threadIdx.x >> 6;
    const int lane = threadIdx.x & 63;
    const int b = blockIdx.x * 4 + wave;
    const u16* row = h1b + (size_t)b * N1;
    float s = 0.f;
    #pragma unroll
    for (int i = 0; i < 8; ++i) {
        int k = lane + i * 64;
        s = fmaf(bf2f(row[k]), w_out[k], s);
    }
    #pragma unroll
    for (int off = 32; off; off >>= 1) s += __shfl_down(s, off, 64);
    if (lane == 0) out[b] = 1.f / (1.f + expf(-(s + b_out[0])));
}

// ---------------------------------------------------------------------------
extern "C" void kernel_launch(void* const* d_in, const int* in_sizes, int n_in,
                              void* d_out, int out_size, void* d_ws, size_t ws_size,
                              hipStream_t stream)
{
    const int*   x     = (const int*)  d_in[0];
    const float* emb   = (const float*)d_in[1];
    const float* w_c   = (const float*)d_in[2];
    const float* b_c   = (const float*)d_in[3];
    const float* g_c   = (const float*)d_in[4];
    const float* be_c  = (const float*)d_in[5];
    const float* w0    = (const float*)d_in[6];
    const float* b0    = (const float*)d_in[7];
    const float* g0    = (const float*)d_in[8];
    const float* be0   = (const float*)d_in[9];
    const float* w1    = (const float*)d_in[10];
    const float* b1    = (const float*)d_in[11];
    const float* g1    = (const float*)d_in[12];
    const float* be1   = (const float*)d_in[13];
    const float* w_out = (const float*)d_in[14];
    const float* b_out = (const float*)d_in[15];
    float* out = (float*)d_out;

    // workspace layout (~97.4 MB)
    u16*   flatb = (u16*)d_ws;                          // B*640*2  = 20.97 MB
    u16*   zb    = flatb + (size_t)B_SZ * KP0;          // 20.97 MB
    u16*   w0b   = zb    + (size_t)B_SZ * KP0;          // 1.31 MB
    u16*   h0b   = w0b   + (size_t)N0 * KP0;            // 33.55 MB
    u16*   w1b   = h0b   + (size_t)B_SZ * N0;           // 1.05 MB
    u16*   h1b   = w1b   + (size_t)N1 * N0;             // 16.78 MB
    u16*   wcb   = h1b   + (size_t)B_SZ * N1;           // 0.08 MB
    float* wsel  = (float*)(wcb + (size_t)NCP * KP0);   // B*40*4 = 2.62 MB
    float* bcp   = wsel + (size_t)B_SZ * WSL;
    float* gcp   = bcp + NCP;
    float* becp  = gcp + NCP;

    pad_params_kernel<<<1, NCP, 0, stream>>>(b_c, g_c, be_c, bcp, gcp, becp);
    prep_wc_kernel<<<(NCP * KP0 + 255) / 256, 256, 0, stream>>>(w_c, wcb);
    prep_w0_kernel<<<(N0 * KP0 + 255) / 256, 256, 0, stream>>>(w0, w0b);
    convert_kernel<<<(N1 * N0 + 255) / 256, 256, 0, stream>>>(w1, w1b, N1 * N0);

    gather_kernel<<<GBLOCKS + B_SZ / 256, 256, 0, stream>>>(x, emb, flatb);

    controller_gemm_select_kernel<<<B_SZ / 64, 256, 0, stream>>>(
        flatb, wcb, bcp, gcp, becp, wsel);

    select_scale_kernel<<<(B_SZ * (KP0 / 8)) / 256, 256, 0, stream>>>(flatb, wsel, zb);

    gemm_mfma_bn_relu<1><<<dim3(B_SZ / 128, N0 / 128), 256, 0, stream>>>(
        zb, w0b, b0, g0, be0, h0b, B_SZ, N0, KP0);
    gemm_mfma_bn_relu<1><<<dim3(B_SZ / 128, N1 / 128), 256, 0, stream>>>(
        h0b, w1b, b1, g1, be1, h1b, B_SZ, N1, N0);

    out_kernel<<<B_SZ / 4, 256, 0, stream>>>(h1b, w_out, b_out, out);
}

// Round 5
// 243.873 us; speedup vs baseline: 3.2587x; 1.0478x over previous
//
#include <hip/hip_runtime.h>
#include <math.h>

#define B_SZ 16384
#define F_N 39
#define V_N 30000
#define D_N 16
#define K_SEL 20
#define FD 624     // F_N * D_N
#define KP0 640    // controller/GEMM0 K padded to multiple of 32
#define NCP 48     // controller GEMM padded N (>= 39, 3 n-tiles of 16)
#define N0 1024
#define N1 512
#define CBR 16     // batch rows per fused-controller block (one wave)
#define ALD 648    // LDS row stride (u16) for gathered A: 16B-aligned, 2-way banks

typedef unsigned short u16;
typedef __attribute__((ext_vector_type(8))) short bf16x8;
typedef __attribute__((ext_vector_type(8))) unsigned short u16x8;
typedef __attribute__((ext_vector_type(4))) float f32x4;
typedef __attribute__((ext_vector_type(4))) unsigned short u16x4;

__device__ __forceinline__ u16 f2bf(float v) {
    union { float f; unsigned u; } x; x.f = v;
    unsigned r = x.u + 0x7fff + ((x.u >> 16) & 1);   // RNE
    return (u16)(r >> 16);
}
__device__ __forceinline__ float bf2f(u16 v) {
    union { unsigned u; float f; } x; x.u = ((unsigned)v) << 16;
    return x.f;
}

#define GLD16(gp, lp) __builtin_amdgcn_global_load_lds( \
    (const __attribute__((address_space(1))) unsigned int*)(gp), \
    (__attribute__((address_space(3))) unsigned int*)(lp), 16, 0, 0)

// ---------------------------------------------------------------------------
// Prep kernels
// ---------------------------------------------------------------------------
__global__ void convert_kernel(const float* __restrict__ src, u16* __restrict__ dst,
                               int n_el)
{
    int i = blockIdx.x * blockDim.x + threadIdx.x;
    if (i < n_el) dst[i] = f2bf(src[i]);
}

// w0p[n][f*16+d] = bf16(w0[n][d*39+f]), zero-pad cols 624..639
__global__ void prep_w0_kernel(const float* __restrict__ w0, u16* __restrict__ w0p)
{
    int i = blockIdx.x * blockDim.x + threadIdx.x;
    if (i >= N0 * KP0) return;
    int n = i / KP0, kk = i - n * KP0;
    float v = 0.f;
    if (kk < FD) {
        int f = kk >> 4, d = kk & 15;
        v = w0[n * FD + d * F_N + f];
    }
    w0p[i] = f2bf(v);
}

// wcb[n][f*16+d] = bf16(w_c[n][d*39+f]), zero-pad n to 48 rows, k to 640
__global__ void prep_wc_kernel(const float* __restrict__ w_c, u16* __restrict__ wcb)
{
    int i = blockIdx.x * blockDim.x + threadIdx.x;
    if (i >= NCP * KP0) return;
    int n = i / KP0, kk = i - n * KP0;
    float v = 0.f;
    if (n < F_N && kk < FD) {
        int f = kk >> 4, d = kk & 15;
        v = w_c[n * FD + d * F_N + f];
    }
    wcb[i] = f2bf(v);
}

// pad controller bn params 39 -> 48
__global__ void pad_params_kernel(const float* __restrict__ b_c,
                                  const float* __restrict__ g_c,
                                  const float* __restrict__ be_c,
                                  float* __restrict__ bp, float* __restrict__ gp,
                                  float* __restrict__ bep)
{
    int n = threadIdx.x;
    bp[n]  = (n < F_N) ? b_c[n]  : 0.f;
    gp[n]  = (n < F_N) ? g_c[n]  : 0.f;
    bep[n] = (n < F_N) ? be_c[n] : 0.f;
}

// ---------------------------------------------------------------------------
// Fused controller: gather -> LDS, 16x48 MFMA GEMM, bn/relu, softmax, top-K
// rank, select-scale -> zb.  One wave (64 thr) per 16 batch rows, no global
// flatb/wsel intermediates, no barriers in the K-loop.
// ---------------------------------------------------------------------------
__global__ __launch_bounds__(64) void fused_controller_kernel(
    const int* __restrict__ x, const float* __restrict__ emb_table,
    const u16* __restrict__ wcb, const float* __restrict__ bcp,
    const float* __restrict__ gcp, const float* __restrict__ becp,
    u16* __restrict__ zb)
{
    __shared__ __align__(16) u16 Al[CBR * ALD];   // gathered A, bf16, [row][k]
    __shared__ float vv[CBR][49];                 // scores / exp values

    const int lane = threadIdx.x;
    const int b0   = blockIdx.x * CBR;
    const int row  = lane >> 2;          // 0..15 (gather/select mapping)
    const int fg   = lane & 3;           // 0..3

    // ---- gather: lane covers f = fg, fg+4, ... for its row ----
    #pragma unroll
    for (int it = 0; it < 10; ++it) {
        const int f = fg + 4 * it;
        if (f < F_N) {
            const int xi = x[(b0 + row) * F_N + f];
            const float4* src =
                (const float4*)(emb_table + (size_t)(xi + f * V_N) * D_N);
            float4 v0 = src[0], v1 = src[1], v2 = src[2], v3 = src[3];
            u16x8 o0 = { f2bf(v0.x), f2bf(v0.y), f2bf(v0.z), f2bf(v0.w),
                         f2bf(v1.x), f2bf(v1.y), f2bf(v1.z), f2bf(v1.w) };
            u16x8 o1 = { f2bf(v2.x), f2bf(v2.y), f2bf(v2.z), f2bf(v2.w),
                         f2bf(v3.x), f2bf(v3.y), f2bf(v3.z), f2bf(v3.w) };
            *(u16x8*)&Al[row * ALD + f * D_N]     = o0;
            *(u16x8*)&Al[row * ALD + f * D_N + 8] = o1;
        }
    }
    __syncthreads();

    // ---- GEMM: hc[16][48] = Al @ wcb^T  (3 n-tiles, K=640) ----
    const int m = lane & 15;             // MFMA fragment row/col index
    const int q = lane >> 4;             // 0..3, k-unit
    f32x4 acc0 = {}, acc1 = {}, acc2 = {};
    const u16* ap  = &Al[m * ALD + q * 8];
    const u16* bp0 = wcb + (size_t)(0  + m) * KP0 + q * 8;
    const u16* bp1 = wcb + (size_t)(16 + m) * KP0 + q * 8;
    const u16* bp2 = wcb + (size_t)(32 + m) * KP0 + q * 8;
    #pragma unroll 4
    for (int k0 = 0; k0 < KP0; k0 += 32) {
        bf16x8 af = *(const bf16x8*)ap;
        bf16x8 b0 = *(const bf16x8*)bp0;
        bf16x8 b1 = *(const bf16x8*)bp1;
        bf16x8 b2 = *(const bf16x8*)bp2;
        acc0 = __builtin_amdgcn_mfma_f32_16x16x32_bf16(af, b0, acc0, 0, 0, 0);
        acc1 = __builtin_amdgcn_mfma_f32_16x16x32_bf16(af, b1, acc1, 0, 0, 0);
        acc2 = __builtin_amdgcn_mfma_f32_16x16x32_bf16(af, b2, acc2, 0, 0, 0);
        ap += 32; bp0 += 32; bp1 += 32; bp2 += 32;
    }

    // ---- bn + relu -> vv[m_out][n];  C-layout: col=lane&15, row=q*4+r ----
    const float rs = rsqrtf(1.0f + 1e-5f);
    #pragma unroll
    for (int j = 0; j < 3; ++j) {
        const f32x4 a = (j == 0) ? acc0 : (j == 1) ? acc1 : acc2;
        const int n = j * 16 + m;
        const float gn = gcp[n] * rs;
        const float bn = becp[n];
        const float bi = bcp[n];
        #pragma unroll
        for (int r = 0; r < 4; ++r)
            vv[q * 4 + r][n] = fmaxf(fmaf(gn, a[r] + bi, bn), 0.f);
    }
    __syncthreads();

    // ---- softmax over 39 (quad-cooperative: 4 lanes per row) ----
    float e[10];
    float mloc = -1e30f;
    #pragma unroll
    for (int it = 0; it < 10; ++it) {
        const int f = fg + 4 * it;
        if (f < F_N) { e[it] = vv[row][f]; mloc = fmaxf(mloc, e[it]); }
    }
    mloc = fmaxf(mloc, __shfl_xor(mloc, 1, 64));
    mloc = fmaxf(mloc, __shfl_xor(mloc, 2, 64));
    float sloc = 0.f;
    #pragma unroll
    for (int it = 0; it < 10; ++it) {
        const int f = fg + 4 * it;
        if (f < F_N) { e[it] = expf(e[it] - mloc); sloc += e[it]; }
    }
    sloc += __shfl_xor(sloc, 1, 64);
    sloc += __shfl_xor(sloc, 2, 64);
    const float inv = 1.f / sloc;
    #pragma unroll
    for (int it = 0; it < 10; ++it) {
        const int f = fg + 4 * it;
        if (f < F_N) vv[row][f] = e[it];
    }
    __syncthreads();

    // ---- top-K rank (lax.top_k tie-break: ties -> lower index) ----
    int rank[10] = {};
    for (int gg = 0; gg < F_N; ++gg) {
        const float o = vv[row][gg];
        #pragma unroll
        for (int it = 0; it < 10; ++it) {
            const int f = fg + 4 * it;
            if (f < F_N)
                rank[it] += (o > e[it] || (o == e[it] && gg < f)) ? 1 : 0;
        }
    }

    // ---- select-scale -> zb (bf16, k-order f*16+d, cols 624..639 zero) ----
    #pragma unroll
    for (int it = 0; it < 10; ++it) {
        const int f = fg + 4 * it;
        u16* dst = zb + (size_t)(b0 + row) * KP0 + f * D_N;
        if (f < F_N) {
            const float w = (rank[it] < K_SEL) ? e[it] * inv : 0.f;
            u16x8 a0 = *(u16x8*)&Al[row * ALD + f * D_N];
            u16x8 a1 = *(u16x8*)&Al[row * ALD + f * D_N + 8];
            u16x8 o0, o1;
            #pragma unroll
            for (int k = 0; k < 8; ++k) {
                o0[k] = f2bf(bf2f(a0[k]) * w);
                o1[k] = f2bf(bf2f(a1[k]) * w);
            }
            *(u16x8*)dst = o0;
            *(u16x8*)(dst + 8) = o1;
        } else if (f == F_N) {          // pad slot kk = 624..639
            u16x8 zz = {0, 0, 0, 0, 0, 0, 0, 0};
            *(u16x8*)dst = zz;
            *(u16x8*)(dst + 8) = zz;
        }
    }
}

// ---------------------------------------------------------------------------
// MFMA GEMM: C[M,N] = relu(bn(A[M,Kp] @ W[N,Kp]^T + bias)); 128x128 tile.
// M-panel on blockIdx.x (fastest) -> XCD-local A reuse.
// ---------------------------------------------------------------------------
template<int STORE_BF16>
__global__ __launch_bounds__(256) void gemm_mfma_bn_relu(
    const u16* __restrict__ A, const u16* __restrict__ W,
    const float* __restrict__ bias, const float* __restrict__ g,
    const float* __restrict__ be, void* __restrict__ Cout,
    int M, int N, int Kp)
{
    __shared__ __align__(16) u16 As[128 * 32];
    __shared__ __align__(16) u16 Bs[128 * 32];

    const int t    = threadIdx.x;
    const int wave = t >> 6;
    const int lane = t & 63;
    const int wm   = wave >> 1, wn = wave & 1;
    const int m0   = blockIdx.x * 128;
    const int n0   = blockIdx.y * 128;

    const int lr    = lane >> 2;
    const int swz_u = (lane & 3) ^ ((lane >> 3) & 3);
    const u16* gA0 = A + (size_t)(m0 + wave * 32 + lr) * Kp + swz_u * 8;
    const u16* gA1 = gA0 + 16 * (size_t)Kp;
    const u16* gB0 = W + (size_t)(n0 + wave * 32 + lr) * Kp + swz_u * 8;
    const u16* gB1 = gB0 + 16 * (size_t)Kp;
    u16* lA0 = &As[(wave * 32)      * 32];
    u16* lA1 = &As[(wave * 32 + 16) * 32];
    u16* lB0 = &Bs[(wave * 32)      * 32];
    u16* lB1 = &Bs[(wave * 32 + 16) * 32];

    const int q    = lane >> 4;
    const int lr16 = lane & 15;

    int aoff[4], boff[4];
    #pragma unroll
    for (int i = 0; i < 4; ++i) {
        int ra = wm * 64 + i * 16 + lr16;
        aoff[i] = ra * 32 + ((q ^ ((ra >> 1) & 3)) * 8);
        int rb = wn * 64 + i * 16 + lr16;
        boff[i] = rb * 32 + ((q ^ ((rb >> 1) & 3)) * 8);
    }

    f32x4 acc[4][4] = {};

    for (int k0 = 0; k0 < Kp; k0 += 32) {
        GLD16(gA0, lA0); GLD16(gA1, lA1);
        GLD16(gB0, lB0); GLD16(gB1, lB1);
        gA0 += 32; gA1 += 32; gB0 += 32; gB1 += 32;
        __syncthreads();

        bf16x8 af[4], bfr[4];
        #pragma unroll
        for (int i = 0; i < 4; ++i) af[i]  = *(const bf16x8*)&As[aoff[i]];
        #pragma unroll
        for (int j = 0; j < 4; ++j) bfr[j] = *(const bf16x8*)&Bs[boff[j]];

        #pragma unroll
        for (int i = 0; i < 4; ++i)
            #pragma unroll
            for (int j = 0; j < 4; ++j)
                acc[i][j] = __builtin_amdgcn_mfma_f32_16x16x32_bf16(
                    af[i], bfr[j], acc[i][j], 0, 0, 0);
        __syncthreads();
    }

    const float rs = rsqrtf(1.0f + 1e-5f);
    #pragma unroll
    for (int j = 0; j < 4; ++j) {
        const int n = n0 + wn * 64 + j * 16 + lr16;
        const float bn_g = g[n] * rs;
        const float bn_b = be[n];
        const float bi   = bias[n];
        #pragma unroll
        for (int i = 0; i < 4; ++i) {
            const int mbase = m0 + wm * 64 + i * 16 + q * 4;
            #pragma unroll
            for (int r = 0; r < 4; ++r) {
                float v = acc[i][j][r] + bi;
                v = fmaxf(fmaf(bn_g, v, bn_b), 0.f);
                const size_t off = (size_t)(mbase + r) * N + n;
                if (STORE_BF16) ((u16*)Cout)[off] = f2bf(v);
                else            ((float*)Cout)[off] = v;
            }
        }
    }
}

// ---------------------------------------------------------------------------
// out[b] = sigmoid(dot(h1b[b,:512], w_out) + b_out); one wave per row
// ---------------------------------------------------------------------------
__global__ __launch_bounds__(256) void out_kernel(
    const u16* __restrict__ h1b, const float* __restrict__ w_out,
    const float* __restrict__ b_out, float* __restrict__ out)
{
    const int wave = threadIdx.x >> 6;
    const int lane = threadIdx.x & 63;
    const int b = blockIdx.x * 4 + wave;
    const u16* row = h1b + (size_t)b * N1;
    float s = 0.f;
    #pragma unroll
    for (int i = 0; i < 8; ++i) {
        int k = lane + i * 64;
        s = fmaf(bf2f(row[k]), w_out[k], s);
    }
    #pragma unroll
    for (int off = 32; off; off >>= 1) s += __shfl_down(s, off, 64);
    if (lane == 0) out[b] = 1.f / (1.f + expf(-(s + b_out[0])));
}

// ---------------------------------------------------------------------------
extern "C" void kernel_launch(void* const* d_in, const int* in_sizes, int n_in,
                              void* d_out, int out_size, void* d_ws, size_t ws_size,
                              hipStream_t stream)
{
    const int*   x     = (const int*)  d_in[0];
    const float* emb   = (const float*)d_in[1];
    const float* w_c   = (const float*)d_in[2];
    const float* b_c   = (const float*)d_in[3];
    const float* g_c   = (const float*)d_in[4];
    const float* be_c  = (const float*)d_in[5];
    const float* w0    = (const float*)d_in[6];
    const float* b0    = (const float*)d_in[7];
    const float* g0    = (const float*)d_in[8];
    const float* be0   = (const float*)d_in[9];
    const float* w1    = (const float*)d_in[10];
    const float* b1    = (const float*)d_in[11];
    const float* g1    = (const float*)d_in[12];
    const float* be1   = (const float*)d_in[13];
    const float* w_out = (const float*)d_in[14];
    const float* b_out = (const float*)d_in[15];
    float* out = (float*)d_out;

    // workspace layout (~75 MB)
    u16*   zb    = (u16*)d_ws;                          // B*640*2  = 20.97 MB
    u16*   w0b   = zb    + (size_t)B_SZ * KP0;          // 1.31 MB
    u16*   h0b   = w0b   + (size_t)N0 * KP0;            // 33.55 MB
    u16*   w1b   = h0b   + (size_t)B_SZ * N0;           // 1.05 MB
    u16*   h1b   = w1b   + (size_t)N1 * N0;             // 16.78 MB
    u16*   wcb   = h1b   + (size_t)B_SZ * N1;           // 0.06 MB
    float* bcp   = (float*)(wcb + (size_t)NCP * KP0);
    float* gcp   = bcp + NCP;
    float* becp  = gcp + NCP;

    pad_params_kernel<<<1, NCP, 0, stream>>>(b_c, g_c, be_c, bcp, gcp, becp);
    prep_wc_kernel<<<(NCP * KP0 + 255) / 256, 256, 0, stream>>>(w_c, wcb);
    prep_w0_kernel<<<(N0 * KP0 + 255) / 256, 256, 0, stream>>>(w0, w0b);
    convert_kernel<<<(N1 * N0 + 255) / 256, 256, 0, stream>>>(w1, w1b, N1 * N0);

    fused_controller_kernel<<<B_SZ / CBR, 64, 0, stream>>>(
        x, emb, wcb, bcp, gcp, becp, zb);

    gemm_mfma_bn_relu<1><<<dim3(B_SZ / 128, N0 / 128), 256, 0, stream>>>(
        zb, w0b, b0, g0, be0, h0b, B_SZ, N0, KP0);
    gemm_mfma_bn_relu<1><<<dim3(B_SZ / 128, N1 / 128), 256, 0, stream>>>(
        h0b, w1b, b1, g1, be1, h1b, B_SZ, N1, N0);

    out_kernel<<<B_SZ / 4, 256, 0, stream>>>(h1b, w_out, b_out, out);
}